// Round 1
// baseline (249.878 us; speedup 1.0000x reference)
//
#include <hip/hip_runtime.h>

// SSIM, fused: reflect-pad(1) + five 3x3 box filters + elementwise formula.
// NCHW 32x3x384x640 fp32.
//
// v2: latency-bound fix (prior: 24 VGPR, 6 scalar loads in flight/wave, 2.45 TB/s).
//  - Each thread owns 4 columns (float4 loads, 16B/lane) and walks KROWS rows.
//  - Rolling 3-row window of horizontal 3-tap sums in registers (each input row
//    read exactly once per thread: 2x float4 + 4 halo scalars).
//  - 2-deep software pipeline: raw loads for row i+2 issue one full iteration
//    before use -> ~6KB in flight per wave instead of ~1.5KB.
//  - Nontemporal float4 stores (output never re-read; keep x/y L3-resident).

constexpr int HH = 384;
constexpr int WW = 640;
constexpr int VEC = 4;              // columns per thread (float4)
constexpr int KROWS = 16;           // rows per thread; halo amortization 18/16
constexpr int BW = 64;              // threads per block = 1 wave
constexpr int TCOLS = WW / VEC;     // 160 thread-columns per image row
constexpr float C1 = 0.01f * 0.01f;
constexpr float C2 = 0.03f * 0.03f;

typedef float f32x4 __attribute__((ext_vector_type(4)));

__global__ __launch_bounds__(BW) void ssim_kernel(
    const float* __restrict__ x,
    const float* __restrict__ y,
    float* __restrict__ out)
{
    const int tc = blockIdx.x * BW + threadIdx.x;
    if (tc >= TCOLS) return;                  // grid.x=3 covers 192; mask 32
    const int c0 = tc * VEC;
    const int h0 = blockIdx.y * KROWS;
    const size_t pbase = (size_t)blockIdx.z * (size_t)(HH * WW);
    const float* __restrict__ xp = x + pbase;
    const float* __restrict__ yp = y + pbase;
    float* __restrict__ op = out + pbase;

    // reflect (jnp 'reflect': edge NOT repeated): -1 -> 1, W -> W-2
    const int wl = (c0 == 0) ? 1 : (c0 - 1);
    const int wr = (c0 + VEC >= WW) ? (WW - 2) : (c0 + VEC);

    // raw 6-tap row values, double-buffered for the 2-deep pipeline
    float rx[2][6], ry[2][6];
    // rolling 3-row window of horizontal sums, 4 columns each
    float hx[3][4], hy[3][4], hxx[3][4], hyy[3][4], hxy[3][4];

#define LOAD_RAW(R, B) do {                                              \
        int rr = (R);                                                    \
        rr = (rr < 0) ? 1 : ((rr >= HH) ? (HH - 2) : rr);                \
        const float* __restrict__ xr = xp + (size_t)rr * WW;             \
        const float* __restrict__ yr = yp + (size_t)rr * WW;             \
        const f32x4 vx = *reinterpret_cast<const f32x4*>(xr + c0);       \
        const f32x4 vy = *reinterpret_cast<const f32x4*>(yr + c0);       \
        const float xlh = xr[wl], xrh = xr[wr];                          \
        const float ylh = yr[wl], yrh = yr[wr];                          \
        rx[B][0] = xlh; rx[B][1] = vx.x; rx[B][2] = vx.y;                \
        rx[B][3] = vx.z; rx[B][4] = vx.w; rx[B][5] = xrh;                \
        ry[B][0] = ylh; ry[B][1] = vy.x; ry[B][2] = vy.y;                \
        ry[B][3] = vy.z; ry[B][4] = vy.w; ry[B][5] = yrh;                \
    } while (0)

#define HSUM(J, B) do {                                                  \
        _Pragma("unroll")                                                \
        for (int c = 0; c < VEC; ++c) {                                  \
            const float a0 = rx[B][c], a1 = rx[B][c + 1], a2 = rx[B][c + 2]; \
            const float b0 = ry[B][c], b1 = ry[B][c + 1], b2 = ry[B][c + 2]; \
            hx[J][c]  = a0 + a1 + a2;                                    \
            hy[J][c]  = b0 + b1 + b2;                                    \
            hxx[J][c] = a0 * a0 + a1 * a1 + a2 * a2;                     \
            hyy[J][c] = b0 * b0 + b1 * b1 + b2 * b2;                     \
            hxy[J][c] = a0 * b0 + a1 * b1 + a2 * b2;                     \
        }                                                                \
    } while (0)

    // Prologue: rows h0-1 and h0 (loads overlap via separate buffers),
    // then prefetch raw row h0+1 into buffer 0.
    LOAD_RAW(h0 - 1, 0);
    LOAD_RAW(h0,     1);
    HSUM(0, 0);
    HSUM(1, 1);
    LOAD_RAW(h0 + 1, 0);

    const float inv9 = 1.0f / 9.0f;

#pragma unroll
    for (int i = 0; i < KROWS; ++i) {
        const int cur = i & 1;        // buffer holding raw row h0+i+1
        const int nxt = cur ^ 1;
        if (i < KROWS - 1) LOAD_RAW(h0 + i + 2, nxt);   // issue next row early
        HSUM((i + 2) % 3, cur);

        float o[VEC];
#pragma unroll
        for (int c = 0; c < VEC; ++c) {
            const float sx  = hx[0][c]  + hx[1][c]  + hx[2][c];
            const float sy  = hy[0][c]  + hy[1][c]  + hy[2][c];
            const float sxx = hxx[0][c] + hxx[1][c] + hxx[2][c];
            const float syy = hyy[0][c] + hyy[1][c] + hyy[2][c];
            const float sxy = hxy[0][c] + hxy[1][c] + hxy[2][c];

            const float mux = sx * inv9;
            const float muy = sy * inv9;
            const float varx = sxx * inv9 - mux * mux;
            const float vary = syy * inv9 - muy * muy;
            const float cov  = sxy * inv9 - mux * muy;

            const float num = (2.0f * mux * muy + C1) * (2.0f * cov + C2);
            const float den = (mux * mux + muy * muy + C1) * (varx + vary + C2);
            float s = num / den;
            o[c] = fminf(fmaxf(s, 0.0f), 1.0f);
        }

        f32x4 ov;
        ov.x = o[0]; ov.y = o[1]; ov.z = o[2]; ov.w = o[3];
        __builtin_nontemporal_store(
            ov, reinterpret_cast<f32x4*>(op + (size_t)(h0 + i) * WW + c0));
    }
#undef LOAD_RAW
#undef HSUM
}

extern "C" void kernel_launch(void* const* d_in, const int* in_sizes, int n_in,
                              void* d_out, int out_size, void* d_ws, size_t ws_size,
                              hipStream_t stream) {
    const float* x = (const float*)d_in[0];
    const float* y = (const float*)d_in[1];
    float* out = (float*)d_out;

    const int planes = in_sizes[0] / (HH * WW);        // 32*3 = 96
    dim3 grid((TCOLS + BW - 1) / BW, HH / KROWS, planes);  // (3, 24, 96)
    dim3 block(BW);
    ssim_kernel<<<grid, block, 0, stream>>>(x, y, out);
}